// Round 3
// baseline (247.080 us; speedup 1.0000x reference)
//
#include <hip/hip_runtime.h>
#include <hip/hip_bf16.h>

#define IN_F 4096
#define OUT_F 4096
#define CPN 81
#define OINV 2225   // 81^{-1} mod 4096
#define BATCH 16384

#define BM 32       // batch rows per block (pass 1)
#define GPB 16      // groups of 16 outputs per block -> 256 outputs/block
#define NC4 88      // float4 staged per row (352 cols >= 336 needed)
#define LDSTR 360   // LDS row stride in bf16 elems (odd multiple of 8 -> bank spread)

typedef __attribute__((ext_vector_type(4))) float f32x4;
typedef __attribute__((ext_vector_type(8))) short bf16x8;
typedef __attribute__((ext_vector_type(8))) unsigned short u16x8;

__device__ __forceinline__ unsigned short f2bf(float f) {
  __hip_bfloat16 h = __float2bfloat16(f);
  return *reinterpret_cast<unsigned short*>(&h);
}
__device__ __forceinline__ float bf2f(unsigned short u) {
  unsigned int v = ((unsigned int)u) << 16;
  return *reinterpret_cast<float*>(&v);
}

// ---- prep: pack weight*mask into MFMA B-fragment order ----
__global__ void prep_wfrag(const float* __restrict__ w,
                           const float* __restrict__ mask,
                           unsigned short* __restrict__ wfrag) {
  int idx = blockIdx.x * 256 + threadIdx.x;   // 49152 threads: (g,t,lane)
  int lane = idx & 63;
  int t = (idx >> 6) % 3;
  int g = idx / 192;
  int n = lane & 15;
  int kg = lane >> 4;
  int s = g * 16 + n;
  int o = (OINV * s) & 4095;
  unsigned short v8[8];
#pragma unroll
  for (int i = 0; i < 8; ++i) {
    int c = 32 * t + 8 * kg + i;
    int j = c - n;
    float v = 0.f;
    if (j >= 0 && j < CPN) {
      int col = (16 * g + c) & 4095;
      v = w[(size_t)o * IN_F + col] * mask[(size_t)o * IN_F + col];
    }
    v8[i] = f2bf(v);
  }
  *reinterpret_cast<bf16x8*>(wfrag + (size_t)idx * 8) =
      *reinterpret_cast<const bf16x8*>(v8);
}

// ---- pass 1: MFMA over dense permuted bands, write ws_t[s][row] bf16 ----
// 4 waves: wave = rtile (rows 16*rtile..+15) + 2*ghalf (groups 8*ghalf..+7)
__global__ __launch_bounds__(256, 6) void sc_main(
    const float* __restrict__ x,
    const unsigned short* __restrict__ wfrag,
    unsigned short* __restrict__ ws) {
  const int bstrip = blockIdx.x;   // 0..511
  const int gb = blockIdx.y;       // 0..15
  const int b0 = bstrip * BM;
  const int S0 = gb * 256;

  __shared__ unsigned short xl[BM * LDSTR];   // 23040 B

  const int tid = threadIdx.x;

  // stage x[32][352] fp32 -> bf16 : 32*88 = 2816 float4, 11 iters exact
#pragma unroll
  for (int k = 0; k < (BM * NC4) / 256; ++k) {
    int idx = tid + k * 256;
    int row = idx / NC4;
    int c4 = idx - row * NC4;
    int col = (S0 + 4 * c4) & 4095;
    const float4 v = *reinterpret_cast<const float4*>(
        x + (size_t)(b0 + row) * IN_F + col);
    ushort4 h;
    h.x = f2bf(v.x); h.y = f2bf(v.y); h.z = f2bf(v.z); h.w = f2bf(v.w);
    *reinterpret_cast<ushort4*>(xl + row * LDSTR + 4 * c4) = h;
  }
  __syncthreads();

  const int wave = tid >> 6;
  const int lane = tid & 63;
  const int ln = lane & 15;        // output col within tile / A row
  const int lk = lane >> 4;        // k-group
  const int rtile = wave & 1;      // row tile: rows 16*rtile .. +15
  const int ghalf = wave >> 1;     // groups 8*ghalf .. +7

  f32x4 acc[8];
#pragma unroll
  for (int g = 0; g < 8; ++g) acc[g] = f32x4{0.f, 0.f, 0.f, 0.f};

  // wfrag layout: ((gb*16 + gg)*3 + t)*64 + lane, 8 bf16 each
  const bf16x8* wf = reinterpret_cast<const bf16x8*>(wfrag)
                   + ((size_t)gb * GPB + 8 * ghalf) * 3 * 64 + lane;
  const unsigned short* arow = xl + (16 * rtile + ln) * LDSTR + 8 * lk;
  const int gcol0 = 16 * 8 * ghalf;   // local col base of this wave's groups

  // prefetch group 0's B frags
  bf16x8 nb0 = wf[0], nb1 = wf[64], nb2 = wf[128];

#pragma unroll
  for (int gi = 0; gi < 8; ++gi) {
    bf16x8 cb0 = nb0, cb1 = nb1, cb2 = nb2;
    if (gi < 7) {
      const bf16x8* nf = wf + (gi + 1) * 192;
      nb0 = nf[0]; nb1 = nf[64]; nb2 = nf[128];
    }
    const unsigned short* ap = arow + gcol0 + 16 * gi;
    bf16x8 a0 = *reinterpret_cast<const bf16x8*>(ap);
    bf16x8 a1 = *reinterpret_cast<const bf16x8*>(ap + 32);
    bf16x8 a2 = *reinterpret_cast<const bf16x8*>(ap + 64);
    acc[gi] = __builtin_amdgcn_mfma_f32_16x16x32_bf16(a0, cb0, acc[gi], 0, 0, 0);
    acc[gi] = __builtin_amdgcn_mfma_f32_16x16x32_bf16(a1, cb1, acc[gi], 0, 0, 0);
    acc[gi] = __builtin_amdgcn_mfma_f32_16x16x32_bf16(a2, cb2, acc[gi], 0, 0, 0);
  }

  // store: D row = 4*lk + r, D col = ln
  const int row0 = b0 + 16 * rtile + 4 * lk;
#pragma unroll
  for (int gi = 0; gi < 8; ++gi) {
    int s = S0 + 16 * (8 * ghalf + gi) + ln;
    ushort4 h;
    h.x = f2bf(acc[gi][0]); h.y = f2bf(acc[gi][1]);
    h.z = f2bf(acc[gi][2]); h.w = f2bf(acc[gi][3]);
    *reinterpret_cast<ushort4*>(ws + (size_t)s * BATCH + row0) = h;
  }
}

// ---- pass 2: permute ws_t[s][row] -> out[row][o] + bias, via LDS tile ----
__global__ __launch_bounds__(256, 4) void sc_perm(
    const unsigned short* __restrict__ ws, const float* __restrict__ bias,
    float* __restrict__ out) {
  const int r0 = blockIdx.x * 128;   // row tile (fast dim)
  const int o0 = blockIdx.y * 64;    // output tile

  __shared__ float t[64 * 129];      // [o_local][row_local]

  const int tid = threadIdx.x;

#pragma unroll
  for (int i = 0; i < 4; ++i) {
    int idx = tid + 256 * i;
    int ol = idx >> 4;          // 0..63
    int seg = idx & 15;         // 8-row segment
    int s = (CPN * (o0 + ol)) & 4095;
    u16x8 v = *reinterpret_cast<const u16x8*>(
        ws + (size_t)s * BATCH + r0 + 8 * seg);
#pragma unroll
    for (int j = 0; j < 8; ++j) t[ol * 129 + 8 * seg + j] = bf2f(v[j]);
  }
  __syncthreads();

  const int wave = tid >> 6;
  const int lane = tid & 63;
  const int o4 = lane & 15;     // 4-output chunk
  const int ro = lane >> 4;     // row offset within wave

  const float4 b4 = *reinterpret_cast<const float4*>(bias + o0 + 4 * o4);

#pragma unroll
  for (int i = 0; i < 8; ++i) {
    int row_l = 16 * i + 4 * wave + ro;   // 0..127
    float4 res;
    res.x = t[(4 * o4 + 0) * 129 + row_l] + b4.x;
    res.y = t[(4 * o4 + 1) * 129 + row_l] + b4.y;
    res.z = t[(4 * o4 + 2) * 129 + row_l] + b4.z;
    res.w = t[(4 * o4 + 3) * 129 + row_l] + b4.w;
    *reinterpret_cast<float4*>(out + (size_t)(r0 + row_l) * OUT_F + o0 + 4 * o4) = res;
  }
}

// fallback epilogue (ws too small): direct scattered write
__global__ __launch_bounds__(256, 3) void sc_main_direct(
    const float* __restrict__ x, const float* __restrict__ bias,
    const unsigned short* __restrict__ wfrag, float* __restrict__ out) {
  const int bstrip = blockIdx.x;
  const int gb = blockIdx.y;
  const int b0 = bstrip * BM;
  const int S0 = gb * 256;
  __shared__ unsigned short xl[BM * LDSTR];
  const int tid = threadIdx.x;
#pragma unroll
  for (int k = 0; k < (BM * NC4) / 256; ++k) {
    int idx = tid + k * 256;
    int row = idx / NC4;
    int c4 = idx - row * NC4;
    int col = (S0 + 4 * c4) & 4095;
    const float4 v = *reinterpret_cast<const float4*>(
        x + (size_t)(b0 + row) * IN_F + col);
    ushort4 h;
    h.x = f2bf(v.x); h.y = f2bf(v.y); h.z = f2bf(v.z); h.w = f2bf(v.w);
    *reinterpret_cast<ushort4*>(xl + row * LDSTR + 4 * c4) = h;
  }
  __syncthreads();
  const int wave = tid >> 6;
  const int lane = tid & 63;
  const int ln = lane & 15;
  const int lk = lane >> 4;
  const int rtile = wave & 1;
  const int ghalf = wave >> 1;
  f32x4 acc[8];
#pragma unroll
  for (int g = 0; g < 8; ++g) acc[g] = f32x4{0.f, 0.f, 0.f, 0.f};
  const bf16x8* wf = reinterpret_cast<const bf16x8*>(wfrag)
                   + ((size_t)gb * GPB + 8 * ghalf) * 3 * 64 + lane;
  const unsigned short* arow = xl + (16 * rtile + ln) * LDSTR + 8 * lk;
  const int gcol0 = 16 * 8 * ghalf;
#pragma unroll
  for (int gi = 0; gi < 8; ++gi) {
    const unsigned short* ap = arow + gcol0 + 16 * gi;
    bf16x8 a0 = *reinterpret_cast<const bf16x8*>(ap);
    bf16x8 a1 = *reinterpret_cast<const bf16x8*>(ap + 32);
    bf16x8 a2 = *reinterpret_cast<const bf16x8*>(ap + 64);
    acc[gi] = __builtin_amdgcn_mfma_f32_16x16x32_bf16(a0, wf[gi*192], acc[gi], 0, 0, 0);
    acc[gi] = __builtin_amdgcn_mfma_f32_16x16x32_bf16(a1, wf[gi*192+64], acc[gi], 0, 0, 0);
    acc[gi] = __builtin_amdgcn_mfma_f32_16x16x32_bf16(a2, wf[gi*192+128], acc[gi], 0, 0, 0);
  }
  const int row0 = b0 + 16 * rtile + 4 * lk;
#pragma unroll
  for (int gi = 0; gi < 8; ++gi) {
    int s = S0 + 16 * (8 * ghalf + gi) + ln;
    int o = (OINV * s) & 4095;
    float bs = bias[o];
#pragma unroll
    for (int r = 0; r < 4; ++r)
      out[(size_t)(row0 + r) * OUT_F + o] = acc[gi][r] + bs;
  }
}

extern "C" void kernel_launch(void* const* d_in, const int* in_sizes, int n_in,
                              void* d_out, int out_size, void* d_ws, size_t ws_size,
                              hipStream_t stream) {
  const float* x    = (const float*)d_in[0];
  const float* w    = (const float*)d_in[1];
  const float* bias = (const float*)d_in[2];
  const float* mask = (const float*)d_in[3];
  float* out = (float*)d_out;

  unsigned short* wfrag = (unsigned short*)d_ws;            // 786432 B
  const size_t WS_OFF = 1u << 20;                            // 1 MB align
  const size_t need = WS_OFF + (size_t)OUT_F * BATCH * 2;    // + 128 MB
  unsigned short* ws_t = (unsigned short*)((char*)d_ws + WS_OFF);

  prep_wfrag<<<192, 256, 0, stream>>>(w, mask, wfrag);

  dim3 grid1(BATCH / BM, OUT_F / (16 * GPB));                // (512, 16)
  if (ws_size >= need) {
    sc_main<<<grid1, 256, 0, stream>>>(x, wfrag, ws_t);
    dim3 grid2(BATCH / 128, OUT_F / 64);                     // (128, 64)
    sc_perm<<<grid2, 256, 0, stream>>>(ws_t, bias, out);
  } else {
    sc_main_direct<<<grid1, 256, 0, stream>>>(x, bias, wfrag, out);
  }
}

// Round 4
// 211.067 us; speedup vs baseline: 1.1706x; 1.1706x over previous
//
#include <hip/hip_runtime.h>
#include <hip/hip_bf16.h>

#define IN_F 4096
#define OUT_F 4096
#define CPN 81
#define OINV 2225   // 81^{-1} mod 4096
#define BATCH 16384
#define WSTR 16416  // ws row stride in elems: 32 KB + 64 B pad (channel de-camp)

#define BM 32       // batch rows per block (pass 1)
#define GPB 16      // groups of 16 outputs per block -> 256 outputs/block
#define NC4 88      // float4 staged per row (352 cols >= 336 needed)
#define LDSTR 360   // LDS row stride in bf16 elems

typedef __attribute__((ext_vector_type(4))) float f32x4;
typedef __attribute__((ext_vector_type(8))) short bf16x8;
typedef __attribute__((ext_vector_type(8))) unsigned short u16x8;

__device__ __forceinline__ unsigned short f2bf(float f) {
  __hip_bfloat16 h = __float2bfloat16(f);
  return *reinterpret_cast<unsigned short*>(&h);
}
__device__ __forceinline__ float bf2f(unsigned short u) {
  unsigned int v = ((unsigned int)u) << 16;
  return *reinterpret_cast<float*>(&v);
}

// ---- prep: pack weight*mask into MFMA B-fragment order ----
__global__ void prep_wfrag(const float* __restrict__ w,
                           const float* __restrict__ mask,
                           unsigned short* __restrict__ wfrag) {
  int idx = blockIdx.x * 256 + threadIdx.x;   // 49152 threads: (g,t,lane)
  int lane = idx & 63;
  int t = (idx >> 6) % 3;
  int g = idx / 192;
  int n = lane & 15;
  int kg = lane >> 4;
  int s = g * 16 + n;
  int o = (OINV * s) & 4095;
  unsigned short v8[8];
#pragma unroll
  for (int i = 0; i < 8; ++i) {
    int c = 32 * t + 8 * kg + i;
    int j = c - n;
    float v = 0.f;
    if (j >= 0 && j < CPN) {
      int col = (16 * g + c) & 4095;
      v = w[(size_t)o * IN_F + col] * mask[(size_t)o * IN_F + col];
    }
    v8[i] = f2bf(v);
  }
  *reinterpret_cast<bf16x8*>(wfrag + (size_t)idx * 8) =
      *reinterpret_cast<const bf16x8*>(v8);
}

// ---- pass 1: MFMA over dense permuted bands, write ws_t[s][row] bf16 ----
// grid (16, 512): gb FAST -> resident blocks span all 16 x-column windows.
__global__ __launch_bounds__(256, 6) void sc_main(
    const float* __restrict__ x,
    const unsigned short* __restrict__ wfrag,
    unsigned short* __restrict__ ws) {
  const int gb = blockIdx.x;       // 0..15  (fast)
  const int bstrip = blockIdx.y;   // 0..511
  const int b0 = bstrip * BM;
  const int S0 = gb * 256;

  __shared__ unsigned short xl[BM * LDSTR];   // 23040 B

  const int tid = threadIdx.x;

  // stage x[32][352] fp32 -> bf16 : 32*88 = 2816 float4, 11 iters exact
#pragma unroll
  for (int k = 0; k < (BM * NC4) / 256; ++k) {
    int idx = tid + k * 256;
    int row = idx / NC4;
    int c4 = idx - row * NC4;
    int col = (S0 + 4 * c4) & 4095;
    const float4 v = *reinterpret_cast<const float4*>(
        x + (size_t)(b0 + row) * IN_F + col);
    ushort4 h;
    h.x = f2bf(v.x); h.y = f2bf(v.y); h.z = f2bf(v.z); h.w = f2bf(v.w);
    *reinterpret_cast<ushort4*>(xl + row * LDSTR + 4 * c4) = h;
  }
  __syncthreads();

  const int wave = tid >> 6;
  const int lane = tid & 63;
  const int ln = lane & 15;        // output col within tile / A row
  const int lk = lane >> 4;        // k-group
  const int rtile = wave & 1;      // rows 16*rtile .. +15
  const int ghalf = wave >> 1;     // groups 8*ghalf .. +7

  f32x4 acc[8];
#pragma unroll
  for (int g = 0; g < 8; ++g) acc[g] = f32x4{0.f, 0.f, 0.f, 0.f};

  const bf16x8* wf = reinterpret_cast<const bf16x8*>(wfrag)
                   + ((size_t)gb * GPB + 8 * ghalf) * 3 * 64 + lane;
  const unsigned short* arow = xl + (16 * rtile + ln) * LDSTR + 8 * lk;
  const int gcol0 = 16 * 8 * ghalf;

  bf16x8 nb0 = wf[0], nb1 = wf[64], nb2 = wf[128];

#pragma unroll
  for (int gi = 0; gi < 8; ++gi) {
    bf16x8 cb0 = nb0, cb1 = nb1, cb2 = nb2;
    if (gi < 7) {
      const bf16x8* nf = wf + (gi + 1) * 192;
      nb0 = nf[0]; nb1 = nf[64]; nb2 = nf[128];
    }
    const unsigned short* ap = arow + gcol0 + 16 * gi;
    bf16x8 a0 = *reinterpret_cast<const bf16x8*>(ap);
    bf16x8 a1 = *reinterpret_cast<const bf16x8*>(ap + 32);
    bf16x8 a2 = *reinterpret_cast<const bf16x8*>(ap + 64);
    acc[gi] = __builtin_amdgcn_mfma_f32_16x16x32_bf16(a0, cb0, acc[gi], 0, 0, 0);
    acc[gi] = __builtin_amdgcn_mfma_f32_16x16x32_bf16(a1, cb1, acc[gi], 0, 0, 0);
    acc[gi] = __builtin_amdgcn_mfma_f32_16x16x32_bf16(a2, cb2, acc[gi], 0, 0, 0);
  }

  const int row0 = b0 + 16 * rtile + 4 * lk;
#pragma unroll
  for (int gi = 0; gi < 8; ++gi) {
    int s = S0 + 16 * (8 * ghalf + gi) + ln;
    ushort4 h;
    h.x = f2bf(acc[gi][0]); h.y = f2bf(acc[gi][1]);
    h.z = f2bf(acc[gi][2]); h.w = f2bf(acc[gi][3]);
    *reinterpret_cast<ushort4*>(ws + (size_t)s * WSTR + row0) = h;
  }
}

// ---- pass 2: permute ws_t[s][row] -> out[row][o] + bias, via LDS tile ----
// grid (64, 128): o0 FAST -> out writes cover full 16 KB channel period;
// ws reads de-camped by WSTR pad.
__global__ __launch_bounds__(256, 4) void sc_perm(
    const unsigned short* __restrict__ ws, const float* __restrict__ bias,
    float* __restrict__ out) {
  const int o0 = blockIdx.x * 64;    // output tile (fast)
  const int r0 = blockIdx.y * 128;   // row tile

  __shared__ float t[64 * 129];      // [o_local][row_local]

  const int tid = threadIdx.x;

#pragma unroll
  for (int i = 0; i < 4; ++i) {
    int idx = tid + 256 * i;
    int ol = idx >> 4;          // 0..63
    int seg = idx & 15;         // 8-row segment
    int s = (CPN * (o0 + ol)) & 4095;
    u16x8 v = *reinterpret_cast<const u16x8*>(
        ws + (size_t)s * WSTR + r0 + 8 * seg);
#pragma unroll
    for (int j = 0; j < 8; ++j) t[ol * 129 + 8 * seg + j] = bf2f(v[j]);
  }
  __syncthreads();

  const int wave = tid >> 6;
  const int lane = tid & 63;
  const int o4 = lane & 15;     // 4-output chunk
  const int ro = lane >> 4;     // row offset within wave

  const float4 b4 = *reinterpret_cast<const float4*>(bias + o0 + 4 * o4);

#pragma unroll
  for (int i = 0; i < 8; ++i) {
    int row_l = 16 * i + 4 * wave + ro;   // 0..127
    float4 res;
    res.x = t[(4 * o4 + 0) * 129 + row_l] + b4.x;
    res.y = t[(4 * o4 + 1) * 129 + row_l] + b4.y;
    res.z = t[(4 * o4 + 2) * 129 + row_l] + b4.z;
    res.w = t[(4 * o4 + 3) * 129 + row_l] + b4.w;
    *reinterpret_cast<float4*>(out + (size_t)(r0 + row_l) * OUT_F + o0 + 4 * o4) = res;
  }
}

// fallback (ws too small): direct scattered write
__global__ __launch_bounds__(256, 3) void sc_main_direct(
    const float* __restrict__ x, const float* __restrict__ bias,
    const unsigned short* __restrict__ wfrag, float* __restrict__ out) {
  const int gb = blockIdx.x;
  const int bstrip = blockIdx.y;
  const int b0 = bstrip * BM;
  const int S0 = gb * 256;
  __shared__ unsigned short xl[BM * LDSTR];
  const int tid = threadIdx.x;
#pragma unroll
  for (int k = 0; k < (BM * NC4) / 256; ++k) {
    int idx = tid + k * 256;
    int row = idx / NC4;
    int c4 = idx - row * NC4;
    int col = (S0 + 4 * c4) & 4095;
    const float4 v = *reinterpret_cast<const float4*>(
        x + (size_t)(b0 + row) * IN_F + col);
    ushort4 h;
    h.x = f2bf(v.x); h.y = f2bf(v.y); h.z = f2bf(v.z); h.w = f2bf(v.w);
    *reinterpret_cast<ushort4*>(xl + row * LDSTR + 4 * c4) = h;
  }
  __syncthreads();
  const int wave = tid >> 6;
  const int lane = tid & 63;
  const int ln = lane & 15;
  const int lk = lane >> 4;
  const int rtile = wave & 1;
  const int ghalf = wave >> 1;
  f32x4 acc[8];
#pragma unroll
  for (int g = 0; g < 8; ++g) acc[g] = f32x4{0.f, 0.f, 0.f, 0.f};
  const bf16x8* wf = reinterpret_cast<const bf16x8*>(wfrag)
                   + ((size_t)gb * GPB + 8 * ghalf) * 3 * 64 + lane;
  const unsigned short* arow = xl + (16 * rtile + ln) * LDSTR + 8 * lk;
  const int gcol0 = 16 * 8 * ghalf;
#pragma unroll
  for (int gi = 0; gi < 8; ++gi) {
    const unsigned short* ap = arow + gcol0 + 16 * gi;
    bf16x8 a0 = *reinterpret_cast<const bf16x8*>(ap);
    bf16x8 a1 = *reinterpret_cast<const bf16x8*>(ap + 32);
    bf16x8 a2 = *reinterpret_cast<const bf16x8*>(ap + 64);
    acc[gi] = __builtin_amdgcn_mfma_f32_16x16x32_bf16(a0, wf[gi*192], acc[gi], 0, 0, 0);
    acc[gi] = __builtin_amdgcn_mfma_f32_16x16x32_bf16(a1, wf[gi*192+64], acc[gi], 0, 0, 0);
    acc[gi] = __builtin_amdgcn_mfma_f32_16x16x32_bf16(a2, wf[gi*192+128], acc[gi], 0, 0, 0);
  }
  const int row0 = b0 + 16 * rtile + 4 * lk;
#pragma unroll
  for (int gi = 0; gi < 8; ++gi) {
    int s = S0 + 16 * (8 * ghalf + gi) + ln;
    int o = (OINV * s) & 4095;
    float bs = bias[o];
#pragma unroll
    for (int r = 0; r < 4; ++r)
      out[(size_t)(row0 + r) * OUT_F + o] = acc[gi][r] + bs;
  }
}

extern "C" void kernel_launch(void* const* d_in, const int* in_sizes, int n_in,
                              void* d_out, int out_size, void* d_ws, size_t ws_size,
                              hipStream_t stream) {
  const float* x    = (const float*)d_in[0];
  const float* w    = (const float*)d_in[1];
  const float* bias = (const float*)d_in[2];
  const float* mask = (const float*)d_in[3];
  float* out = (float*)d_out;

  unsigned short* wfrag = (unsigned short*)d_ws;            // 786432 B
  const size_t WS_OFF = 1u << 20;                            // 1 MB align
  const size_t need = WS_OFF + (size_t)OUT_F * WSTR * 2;     // + ~134.5 MB
  unsigned short* ws_t = (unsigned short*)((char*)d_ws + WS_OFF);

  prep_wfrag<<<192, 256, 0, stream>>>(w, mask, wfrag);

  dim3 grid1(OUT_F / (16 * GPB), BATCH / BM);                // (16, 512) gb fast
  if (ws_size >= need) {
    sc_main<<<grid1, 256, 0, stream>>>(x, wfrag, ws_t);
    dim3 grid2(OUT_F / 64, BATCH / 128);                     // (64, 128) o0 fast
    sc_perm<<<grid2, 256, 0, stream>>>(ws_t, bias, out);
  } else {
    sc_main_direct<<<grid1, 256, 0, stream>>>(x, bias, wfrag, out);
  }
}

// Round 5
// 200.544 us; speedup vs baseline: 1.2321x; 1.0525x over previous
//
#include <hip/hip_runtime.h>
#include <hip/hip_bf16.h>

#define IN_F 4096
#define OUT_F 4096
#define CPN 81
#define OINV 2225   // 81^{-1} mod 4096
#define BATCH 16384
#define WSTR 16416  // ws row stride in elems: 32 KB + 64 B pad (channel de-camp)

#define BM 32       // batch rows per block (pass 1)
#define GPB 16      // groups of 16 outputs per block -> 256 outputs/block
#define NC4 88      // float4 staged per row (352 cols >= 336 needed)
#define LDSTR 360   // LDS row stride in bf16 elems
#define RSTR 36     // res LDS stride in ushorts (72 B: odd*8B -> bank spread)

typedef __attribute__((ext_vector_type(4))) float f32x4;
typedef __attribute__((ext_vector_type(8))) short bf16x8;
typedef __attribute__((ext_vector_type(8))) unsigned short u16x8;

__device__ __forceinline__ unsigned short f2bf(float f) {
  __hip_bfloat16 h = __float2bfloat16(f);
  return *reinterpret_cast<unsigned short*>(&h);
}
__device__ __forceinline__ float bf2f(unsigned short u) {
  unsigned int v = ((unsigned int)u) << 16;
  return *reinterpret_cast<float*>(&v);
}

// ---- prep: pack weight*mask into MFMA B-fragment order ----
__global__ void prep_wfrag(const float* __restrict__ w,
                           const float* __restrict__ mask,
                           unsigned short* __restrict__ wfrag) {
  int idx = blockIdx.x * 256 + threadIdx.x;   // 49152 threads: (g,t,lane)
  int lane = idx & 63;
  int t = (idx >> 6) % 3;
  int g = idx / 192;
  int n = lane & 15;
  int kg = lane >> 4;
  int s = g * 16 + n;
  int o = (OINV * s) & 4095;
  unsigned short v8[8];
#pragma unroll
  for (int i = 0; i < 8; ++i) {
    int c = 32 * t + 8 * kg + i;
    int j = c - n;
    float v = 0.f;
    if (j >= 0 && j < CPN) {
      int col = (16 * g + c) & 4095;
      v = w[(size_t)o * IN_F + col] * mask[(size_t)o * IN_F + col];
    }
    v8[i] = f2bf(v);
  }
  *reinterpret_cast<bf16x8*>(wfrag + (size_t)idx * 8) =
      *reinterpret_cast<const bf16x8*>(v8);
}

// ---- pass 1: MFMA over dense permuted bands, write ws_t[s][row] bf16 ----
// Epilogue assembles full 64 B lines via LDS transpose: thread<->s-row.
__global__ __launch_bounds__(256, 6) void sc_main(
    const float* __restrict__ x,
    const unsigned short* __restrict__ wfrag,
    unsigned short* __restrict__ ws) {
  const int gb = blockIdx.x;       // 0..15  (fast)
  const int bstrip = blockIdx.y;   // 0..511
  const int b0 = bstrip * BM;
  const int S0 = gb * 256;

  __shared__ __align__(16) char smem[BM * LDSTR * 2];   // 23040 B, reused
  unsigned short* xl = (unsigned short*)smem;

  const int tid = threadIdx.x;

  // stage x[32][352] fp32 -> bf16 : 32*88 = 2816 float4, 11 iters exact
#pragma unroll
  for (int k = 0; k < (BM * NC4) / 256; ++k) {
    int idx = tid + k * 256;
    int row = idx / NC4;
    int c4 = idx - row * NC4;
    int col = (S0 + 4 * c4) & 4095;
    const float4 v = *reinterpret_cast<const float4*>(
        x + (size_t)(b0 + row) * IN_F + col);
    ushort4 h;
    h.x = f2bf(v.x); h.y = f2bf(v.y); h.z = f2bf(v.z); h.w = f2bf(v.w);
    *reinterpret_cast<ushort4*>(xl + row * LDSTR + 4 * c4) = h;
  }
  __syncthreads();

  const int wave = tid >> 6;
  const int lane = tid & 63;
  const int ln = lane & 15;        // output col within tile / A row
  const int lk = lane >> 4;        // k-group
  const int rtile = wave & 1;      // rows 16*rtile .. +15
  const int ghalf = wave >> 1;     // groups 8*ghalf .. +7

  f32x4 acc[8];
#pragma unroll
  for (int g = 0; g < 8; ++g) acc[g] = f32x4{0.f, 0.f, 0.f, 0.f};

  const bf16x8* wf = reinterpret_cast<const bf16x8*>(wfrag)
                   + ((size_t)gb * GPB + 8 * ghalf) * 3 * 64 + lane;
  const unsigned short* arow = xl + (16 * rtile + ln) * LDSTR + 8 * lk;
  const int gcol0 = 16 * 8 * ghalf;

  bf16x8 nb0 = wf[0], nb1 = wf[64], nb2 = wf[128];

#pragma unroll
  for (int gi = 0; gi < 8; ++gi) {
    bf16x8 cb0 = nb0, cb1 = nb1, cb2 = nb2;
    if (gi < 7) {
      const bf16x8* nf = wf + (gi + 1) * 192;
      nb0 = nf[0]; nb1 = nf[64]; nb2 = nf[128];
    }
    const unsigned short* ap = arow + gcol0 + 16 * gi;
    bf16x8 a0 = *reinterpret_cast<const bf16x8*>(ap);
    bf16x8 a1 = *reinterpret_cast<const bf16x8*>(ap + 32);
    bf16x8 a2 = *reinterpret_cast<const bf16x8*>(ap + 64);
    acc[gi] = __builtin_amdgcn_mfma_f32_16x16x32_bf16(a0, cb0, acc[gi], 0, 0, 0);
    acc[gi] = __builtin_amdgcn_mfma_f32_16x16x32_bf16(a1, cb1, acc[gi], 0, 0, 0);
    acc[gi] = __builtin_amdgcn_mfma_f32_16x16x32_bf16(a2, cb2, acc[gi], 0, 0, 0);
  }

  __syncthreads();                 // xl dead; reuse smem as res[256][RSTR]
  unsigned short* res = (unsigned short*)smem;

  // scatter accs into res[s_local][row_local] (8 B per store, LDS)
  const int row_l = 16 * rtile + 4 * lk;   // base of this lane's 4 rows
#pragma unroll
  for (int gi = 0; gi < 8; ++gi) {
    int s_l = 128 * ghalf + 16 * gi + ln;
    ushort4 h;
    h.x = f2bf(acc[gi][0]); h.y = f2bf(acc[gi][1]);
    h.z = f2bf(acc[gi][2]); h.w = f2bf(acc[gi][3]);
    *reinterpret_cast<ushort4*>(res + s_l * RSTR + row_l) = h;
  }
  __syncthreads();

  // gather: thread tid <-> s_local; write ONE full 64 B line to ws
  {
    const uint2* rp = reinterpret_cast<const uint2*>(res + tid * RSTR);
    uint2 p0 = rp[0], p1 = rp[1], p2 = rp[2], p3 = rp[3];
    uint2 p4 = rp[4], p5 = rp[5], p6 = rp[6], p7 = rp[7];
    uint4* dst = reinterpret_cast<uint4*>(ws + (size_t)(S0 + tid) * WSTR + b0);
    dst[0] = uint4{p0.x, p0.y, p1.x, p1.y};
    dst[1] = uint4{p2.x, p2.y, p3.x, p3.y};
    dst[2] = uint4{p4.x, p4.y, p5.x, p5.y};
    dst[3] = uint4{p6.x, p6.y, p7.x, p7.y};
  }
}

// ---- pass 2: permute ws_t[s][row] -> out[row][o] + bias, via LDS tile ----
__global__ __launch_bounds__(256, 4) void sc_perm(
    const unsigned short* __restrict__ ws, const float* __restrict__ bias,
    float* __restrict__ out) {
  const int o0 = blockIdx.x * 64;    // output tile (fast)
  const int r0 = blockIdx.y * 128;   // row tile

  __shared__ float t[64 * 129];      // [o_local][row_local]

  const int tid = threadIdx.x;

#pragma unroll
  for (int i = 0; i < 4; ++i) {
    int idx = tid + 256 * i;
    int ol = idx >> 4;          // 0..63
    int seg = idx & 15;         // 8-row segment
    int s = (CPN * (o0 + ol)) & 4095;
    u16x8 v = *reinterpret_cast<const u16x8*>(
        ws + (size_t)s * WSTR + r0 + 8 * seg);
#pragma unroll
    for (int j = 0; j < 8; ++j) t[ol * 129 + 8 * seg + j] = bf2f(v[j]);
  }
  __syncthreads();

  const int wave = tid >> 6;
  const int lane = tid & 63;
  const int o4 = lane & 15;     // 4-output chunk
  const int ro = lane >> 4;     // row offset within wave

  const float4 b4 = *reinterpret_cast<const float4*>(bias + o0 + 4 * o4);

#pragma unroll
  for (int i = 0; i < 8; ++i) {
    int row_l = 16 * i + 4 * wave + ro;   // 0..127
    float4 res;
    res.x = t[(4 * o4 + 0) * 129 + row_l] + b4.x;
    res.y = t[(4 * o4 + 1) * 129 + row_l] + b4.y;
    res.z = t[(4 * o4 + 2) * 129 + row_l] + b4.z;
    res.w = t[(4 * o4 + 3) * 129 + row_l] + b4.w;
    *reinterpret_cast<float4*>(out + (size_t)(r0 + row_l) * OUT_F + o0 + 4 * o4) = res;
  }
}

// fallback (ws too small): direct scattered write
__global__ __launch_bounds__(256, 3) void sc_main_direct(
    const float* __restrict__ x, const float* __restrict__ bias,
    const unsigned short* __restrict__ wfrag, float* __restrict__ out) {
  const int gb = blockIdx.x;
  const int bstrip = blockIdx.y;
  const int b0 = bstrip * BM;
  const int S0 = gb * 256;
  __shared__ unsigned short xl[BM * LDSTR];
  const int tid = threadIdx.x;
#pragma unroll
  for (int k = 0; k < (BM * NC4) / 256; ++k) {
    int idx = tid + k * 256;
    int row = idx / NC4;
    int c4 = idx - row * NC4;
    int col = (S0 + 4 * c4) & 4095;
    const float4 v = *reinterpret_cast<const float4*>(
        x + (size_t)(b0 + row) * IN_F + col);
    ushort4 h;
    h.x = f2bf(v.x); h.y = f2bf(v.y); h.z = f2bf(v.z); h.w = f2bf(v.w);
    *reinterpret_cast<ushort4*>(xl + row * LDSTR + 4 * c4) = h;
  }
  __syncthreads();
  const int wave = tid >> 6;
  const int lane = tid & 63;
  const int ln = lane & 15;
  const int lk = lane >> 4;
  const int rtile = wave & 1;
  const int ghalf = wave >> 1;
  f32x4 acc[8];
#pragma unroll
  for (int g = 0; g < 8; ++g) acc[g] = f32x4{0.f, 0.f, 0.f, 0.f};
  const bf16x8* wf = reinterpret_cast<const bf16x8*>(wfrag)
                   + ((size_t)gb * GPB + 8 * ghalf) * 3 * 64 + lane;
  const unsigned short* arow = xl + (16 * rtile + ln) * LDSTR + 8 * lk;
  const int gcol0 = 16 * 8 * ghalf;
#pragma unroll
  for (int gi = 0; gi < 8; ++gi) {
    const unsigned short* ap = arow + gcol0 + 16 * gi;
    bf16x8 a0 = *reinterpret_cast<const bf16x8*>(ap);
    bf16x8 a1 = *reinterpret_cast<const bf16x8*>(ap + 32);
    bf16x8 a2 = *reinterpret_cast<const bf16x8*>(ap + 64);
    acc[gi] = __builtin_amdgcn_mfma_f32_16x16x32_bf16(a0, wf[gi*192], acc[gi], 0, 0, 0);
    acc[gi] = __builtin_amdgcn_mfma_f32_16x16x32_bf16(a1, wf[gi*192+64], acc[gi], 0, 0, 0);
    acc[gi] = __builtin_amdgcn_mfma_f32_16x16x32_bf16(a2, wf[gi*192+128], acc[gi], 0, 0, 0);
  }
  const int row0 = b0 + 16 * rtile + 4 * lk;
#pragma unroll
  for (int gi = 0; gi < 8; ++gi) {
    int s = S0 + 16 * (8 * ghalf + gi) + ln;
    int o = (OINV * s) & 4095;
    float bs = bias[o];
#pragma unroll
    for (int r = 0; r < 4; ++r)
      out[(size_t)(row0 + r) * OUT_F + o] = acc[gi][r] + bs;
  }
}

extern "C" void kernel_launch(void* const* d_in, const int* in_sizes, int n_in,
                              void* d_out, int out_size, void* d_ws, size_t ws_size,
                              hipStream_t stream) {
  const float* x    = (const float*)d_in[0];
  const float* w    = (const float*)d_in[1];
  const float* bias = (const float*)d_in[2];
  const float* mask = (const float*)d_in[3];
  float* out = (float*)d_out;

  unsigned short* wfrag = (unsigned short*)d_ws;            // 786432 B
  const size_t WS_OFF = 1u << 20;                            // 1 MB align
  const size_t need = WS_OFF + (size_t)OUT_F * WSTR * 2;     // + ~134.5 MB
  unsigned short* ws_t = (unsigned short*)((char*)d_ws + WS_OFF);

  prep_wfrag<<<192, 256, 0, stream>>>(w, mask, wfrag);

  dim3 grid1(OUT_F / (16 * GPB), BATCH / BM);                // (16, 512) gb fast
  if (ws_size >= need) {
    sc_main<<<grid1, 256, 0, stream>>>(x, wfrag, ws_t);
    dim3 grid2(OUT_F / 64, BATCH / 128);                     // (64, 128) o0 fast
    sc_perm<<<grid2, 256, 0, stream>>>(ws_t, bias, out);
  } else {
    sc_main_direct<<<grid1, 256, 0, stream>>>(x, bias, wfrag, out);
  }
}

// Round 6
// 191.131 us; speedup vs baseline: 1.2927x; 1.0492x over previous
//
#include <hip/hip_runtime.h>
#include <hip/hip_bf16.h>

#define IN_F 4096
#define OUT_F 4096
#define CPN 81
#define OINV 2225   // 81^{-1} mod 4096
#define OB16 2832   // 2225*16 mod 4096: o-step per group

#define BMF 8       // batch rows per block
#define NCH 8       // chunks per block
#define CHUNK 512   // band-starts (and x cols) per chunk
#define SC4 148     // float4 staged per row per chunk (592 cols = 512+80... covers 16*31+96)
#define XSTR 616    // x LDS stride in bf16 elems (bank step 20, gcd4 -> spread)
#define RSTRF 8     // res stride in bf16 elems (16 B per o-row)

typedef __attribute__((ext_vector_type(4))) float f32x4;
typedef __attribute__((ext_vector_type(8))) short bf16x8;

__device__ __forceinline__ unsigned short f2bf(float f) {
  __hip_bfloat16 h = __float2bfloat16(f);
  return *reinterpret_cast<unsigned short*>(&h);
}
__device__ __forceinline__ float bf2f(unsigned short u) {
  unsigned int v = ((unsigned int)u) << 16;
  return *reinterpret_cast<float*>(&v);
}

// ---- prep: pack weight*mask into MFMA B-fragment order ----
// wfrag idx = (g*3 + t)*64 + lane; lane: n=lane&15 (s offset), kg=lane>>4.
__global__ void prep_wfrag(const float* __restrict__ w,
                           const float* __restrict__ mask,
                           unsigned short* __restrict__ wfrag) {
  int idx = blockIdx.x * 256 + threadIdx.x;   // 49152 threads
  int lane = idx & 63;
  int t = (idx >> 6) % 3;
  int g = idx / 192;
  int n = lane & 15;
  int kg = lane >> 4;
  int s = g * 16 + n;
  int o = (OINV * s) & 4095;
  unsigned short v8[8];
#pragma unroll
  for (int i = 0; i < 8; ++i) {
    int c = 32 * t + 8 * kg + i;
    int j = c - n;
    float v = 0.f;
    if (j >= 0 && j < CPN) {
      int col = (16 * g + c) & 4095;
      v = w[(size_t)o * IN_F + col] * mask[(size_t)o * IN_F + col];
    }
    v8[i] = f2bf(v);
  }
  *reinterpret_cast<bf16x8*>(wfrag + (size_t)idx * 8) =
      *reinterpret_cast<const bf16x8*>(v8);
}

// ---- fused: 8 rows x all 4096 outputs per block; permute via LDS res ----
__global__ __launch_bounds__(512, 4) void sc_fused(
    const float* __restrict__ x, const float* __restrict__ bias,
    const unsigned short* __restrict__ wfrag, float* __restrict__ out) {
  __shared__ unsigned short res[4096 * RSTRF];   // 65536 B: [o][row] bf16
  __shared__ unsigned short xl[BMF * XSTR];      //  9856 B

  const int blk = blockIdx.x;        // 0..2047
  const int b0 = blk * BMF;
  const int tid = threadIdx.x;
  const int wave = tid >> 6;         // 0..7
  const int lane = tid & 63;
  const int ln = lane & 15;          // MFMA n index (s offset / A row)
  const int lk = lane >> 4;          // k-group / D row quad
  const int oln = (OINV * ln) & 4095;
  const int q0 = blk & 7;            // stagger chunk order across blocks

  for (int qq = 0; qq < NCH; ++qq) {
    const int q = (q0 + qq) & 7;
    const int c0 = q * CHUNK;

    // ---- stage x[8][592] fp32 -> bf16 (1184 float4, 3 guarded iters) ----
#pragma unroll
    for (int k = 0; k < 3; ++k) {
      int idx = tid + k * 512;
      if (idx < BMF * SC4) {
        int row = idx / SC4;
        int c4 = idx - row * SC4;
        int col = (c0 + 4 * c4) & 4095;          // 4-aligned, no straddle
        const float4 v = *reinterpret_cast<const float4*>(
            x + (size_t)(b0 + row) * IN_F + col);
        ushort4 h;
        h.x = f2bf(v.x); h.y = f2bf(v.y); h.z = f2bf(v.z); h.w = f2bf(v.w);
        *reinterpret_cast<ushort4*>(xl + row * XSTR + 4 * c4) = h;
      }
    }
    __syncthreads();

    // ---- compute: 32 groups this chunk, 4 per wave ----
    const unsigned short* arow = xl + (ln & 7) * XSTR + 8 * lk;
#pragma unroll
    for (int j = 0; j < 4; ++j) {
      const int gl = wave * 4 + j;               // local group 0..31
      const int g = q * 32 + gl;                 // global group
      const bf16x8* wf = reinterpret_cast<const bf16x8*>(wfrag)
                       + (size_t)g * 192 + lane;
      const unsigned short* ap = arow + 16 * gl;
      bf16x8 a0 = *reinterpret_cast<const bf16x8*>(ap);
      bf16x8 a1 = *reinterpret_cast<const bf16x8*>(ap + 32);
      bf16x8 a2 = *reinterpret_cast<const bf16x8*>(ap + 64);
      f32x4 acc = f32x4{0.f, 0.f, 0.f, 0.f};
      acc = __builtin_amdgcn_mfma_f32_16x16x32_bf16(a0, wf[0],   acc, 0, 0, 0);
      acc = __builtin_amdgcn_mfma_f32_16x16x32_bf16(a1, wf[64],  acc, 0, 0, 0);
      acc = __builtin_amdgcn_mfma_f32_16x16x32_bf16(a2, wf[128], acc, 0, 0, 0);
      if (lk < 2) {                              // rows 0..7 only (8..15 are dups)
        int o = (OB16 * g + oln) & 4095;         // = (2225*(16g+ln)) mod 4096
        ushort4 h;
        h.x = f2bf(acc[0]); h.y = f2bf(acc[1]);
        h.z = f2bf(acc[2]); h.w = f2bf(acc[3]);
        *reinterpret_cast<ushort4*>(res + o * RSTRF + 4 * lk) = h;
      }
    }
    __syncthreads();   // xl reuse next chunk; after last iter: res complete
  }

  // ---- epilogue: out[b0+r][o] = res[o][r] + bias[o], fully coalesced ----
  const int h8 = tid >> 8;           // 0..1 -> rows 4*h8 .. 4*h8+3
  const int c = tid & 255;           // o low bits (consecutive per wave)
#pragma unroll 4
  for (int i = 0; i < 16; ++i) {
    int o = i * 256 + c;
    const uint2 v = *reinterpret_cast<const uint2*>(res + o * RSTRF + 4 * h8);
    float b = bias[o];
    float r0 = bf2f((unsigned short)(v.x & 0xffff)) + b;
    float r1 = bf2f((unsigned short)(v.x >> 16)) + b;
    float r2 = bf2f((unsigned short)(v.y & 0xffff)) + b;
    float r3 = bf2f((unsigned short)(v.y >> 16)) + b;
    size_t base = (size_t)(b0 + 4 * h8) * OUT_F + o;
    out[base]             = r0;
    out[base + OUT_F]     = r1;
    out[base + 2 * OUT_F] = r2;
    out[base + 3 * OUT_F] = r3;
  }
}

extern "C" void kernel_launch(void* const* d_in, const int* in_sizes, int n_in,
                              void* d_out, int out_size, void* d_ws, size_t ws_size,
                              hipStream_t stream) {
  const float* x    = (const float*)d_in[0];
  const float* w    = (const float*)d_in[1];
  const float* bias = (const float*)d_in[2];
  const float* mask = (const float*)d_in[3];
  float* out = (float*)d_out;

  unsigned short* wfrag = (unsigned short*)d_ws;   // 786432 B

  const int B = in_sizes[0] / IN_F;                // 16384

  prep_wfrag<<<192, 256, 0, stream>>>(w, mask, wfrag);
  sc_fused<<<B / BMF, 512, 0, stream>>>(x, bias, wfrag, out);
}

// Round 7
// 168.104 us; speedup vs baseline: 1.4698x; 1.1370x over previous
//
#include <hip/hip_runtime.h>
#include <hip/hip_bf16.h>

#define IN_F 4096
#define OUT_F 4096
#define CPN 81
#define OINV 2225   // 81^{-1} mod 4096
#define OB16 2832   // 2225*16 mod 4096: o-step per group

#define BMF 8       // batch rows per block
#define NCH 8       // chunks per block
#define CHUNK 512   // band-starts (and x cols) per chunk
#define SC4 148     // float4 staged per row per chunk (592 cols)
#define NLD 1184    // BMF*SC4 total float4 loads per chunk
#define XSTR 616    // x LDS stride in bf16 elems
#define RSTRF 8     // res stride in bf16 elems (16 B per o-row)

typedef __attribute__((ext_vector_type(4))) float f32x4;
typedef __attribute__((ext_vector_type(8))) short bf16x8;

__device__ __forceinline__ unsigned short f2bf(float f) {
  __hip_bfloat16 h = __float2bfloat16(f);
  return *reinterpret_cast<unsigned short*>(&h);
}
__device__ __forceinline__ float bf2f(unsigned short u) {
  unsigned int v = ((unsigned int)u) << 16;
  return *reinterpret_cast<float*>(&v);
}

// ---- prep: pack weight*mask into MFMA B-fragment order ----
__global__ void prep_wfrag(const float* __restrict__ w,
                           const float* __restrict__ mask,
                           unsigned short* __restrict__ wfrag) {
  int idx = blockIdx.x * 256 + threadIdx.x;   // 49152 threads
  int lane = idx & 63;
  int t = (idx >> 6) % 3;
  int g = idx / 192;
  int n = lane & 15;
  int kg = lane >> 4;
  int s = g * 16 + n;
  int o = (OINV * s) & 4095;
  unsigned short v8[8];
#pragma unroll
  for (int i = 0; i < 8; ++i) {
    int c = 32 * t + 8 * kg + i;
    int j = c - n;
    float v = 0.f;
    if (j >= 0 && j < CPN) {
      int col = (16 * g + c) & 4095;
      v = w[(size_t)o * IN_F + col] * mask[(size_t)o * IN_F + col];
    }
    v8[i] = f2bf(v);
  }
  *reinterpret_cast<bf16x8*>(wfrag + (size_t)idx * 8) =
      *reinterpret_cast<const bf16x8*>(v8);
}

// ---- fused, register-pipelined: 8 rows x all 4096 outputs per block ----
__global__ __launch_bounds__(512, 4) void sc_fused(
    const float* __restrict__ x, const float* __restrict__ bias,
    const unsigned short* __restrict__ wfrag, float* __restrict__ out) {
  __shared__ unsigned short res[4096 * RSTRF];   // 65536 B: [o][row] bf16
  __shared__ unsigned short xl[BMF * XSTR];      //  9856 B

  const int blk = blockIdx.x;        // 0..2047
  const int b0 = blk * BMF;
  const int tid = threadIdx.x;
  const int wave = tid >> 6;         // 0..7
  const int lane = tid & 63;
  const int ln = lane & 15;          // MFMA n index (s offset)
  const int lk = lane >> 4;          // k-group / D row quad
  const int oln = (OINV * ln) & 4095;
  const int q0 = blk & 7;            // stagger chunk order across blocks

  // hoisted staging coordinates (3 load slots per thread)
  const int i1 = tid + 512, i2 = tid + 1024;
  const int row0 = tid / SC4, c40 = tid - row0 * SC4;
  const int row1 = i1  / SC4, c41 = i1  - row1 * SC4;
  const int row2 = i2  / SC4, c42 = i2  - row2 * SC4;
  const bool v2 = (i2 < NLD);
  const float* xp0 = x + (size_t)(b0 + row0) * IN_F;
  const float* xp1 = x + (size_t)(b0 + row1) * IN_F;
  const float* xp2 = x + (size_t)(b0 + row2) * IN_F;
  unsigned short* xw0 = xl + row0 * XSTR + 4 * c40;
  unsigned short* xw1 = xl + row1 * XSTR + 4 * c41;
  unsigned short* xw2 = xl + row2 * XSTR + 4 * c42;

  // prologue: load chunk q0 into registers
  float4 xr0, xr1, xr2;
  {
    const int c0 = q0 * CHUNK;
    xr0 = *reinterpret_cast<const float4*>(xp0 + ((c0 + 4 * c40) & 4095));
    xr1 = *reinterpret_cast<const float4*>(xp1 + ((c0 + 4 * c41) & 4095));
    if (v2) xr2 = *reinterpret_cast<const float4*>(xp2 + ((c0 + 4 * c42) & 4095));
  }

  for (int qq = 0; qq < NCH; ++qq) {
    const int q = (q0 + qq) & 7;

    // drain staged regs -> LDS
    {
      ushort4 h;
      h.x = f2bf(xr0.x); h.y = f2bf(xr0.y); h.z = f2bf(xr0.z); h.w = f2bf(xr0.w);
      *reinterpret_cast<ushort4*>(xw0) = h;
      h.x = f2bf(xr1.x); h.y = f2bf(xr1.y); h.z = f2bf(xr1.z); h.w = f2bf(xr1.w);
      *reinterpret_cast<ushort4*>(xw1) = h;
      if (v2) {
        h.x = f2bf(xr2.x); h.y = f2bf(xr2.y); h.z = f2bf(xr2.z); h.w = f2bf(xr2.w);
        *reinterpret_cast<ushort4*>(xw2) = h;
      }
    }
    __syncthreads();

    // issue next chunk's loads (in flight across the compute phase)
    if (qq < NCH - 1) {
      const int c0n = ((q + 1) & 7) * CHUNK;
      xr0 = *reinterpret_cast<const float4*>(xp0 + ((c0n + 4 * c40) & 4095));
      xr1 = *reinterpret_cast<const float4*>(xp1 + ((c0n + 4 * c41) & 4095));
      if (v2) xr2 = *reinterpret_cast<const float4*>(xp2 + ((c0n + 4 * c42) & 4095));
    }

    // compute: 4 groups per wave, prefetch-one-ahead
    const int gbase = q * 32 + wave * 4;
    const bf16x8* wf = reinterpret_cast<const bf16x8*>(wfrag)
                     + (size_t)gbase * 192 + lane;
    const unsigned short* ap = xl + (ln & 7) * XSTR + 8 * lk + 16 * (wave * 4);
    bf16x8 nb0 = wf[0], nb1 = wf[64], nb2 = wf[128];
    bf16x8 na0 = *reinterpret_cast<const bf16x8*>(ap);
    bf16x8 na1 = *reinterpret_cast<const bf16x8*>(ap + 32);
    bf16x8 na2 = *reinterpret_cast<const bf16x8*>(ap + 64);
#pragma unroll
    for (int j = 0; j < 4; ++j) {
      bf16x8 cb0 = nb0, cb1 = nb1, cb2 = nb2;
      bf16x8 ca0 = na0, ca1 = na1, ca2 = na2;
      if (j < 3) {
        const bf16x8* nwf = wf + (j + 1) * 192;
        nb0 = nwf[0]; nb1 = nwf[64]; nb2 = nwf[128];
        const unsigned short* nap = ap + 16 * (j + 1);
        na0 = *reinterpret_cast<const bf16x8*>(nap);
        na1 = *reinterpret_cast<const bf16x8*>(nap + 32);
        na2 = *reinterpret_cast<const bf16x8*>(nap + 64);
      }
      f32x4 acc = f32x4{0.f, 0.f, 0.f, 0.f};
      acc = __builtin_amdgcn_mfma_f32_16x16x32_bf16(ca0, cb0, acc, 0, 0, 0);
      acc = __builtin_amdgcn_mfma_f32_16x16x32_bf16(ca1, cb1, acc, 0, 0, 0);
      acc = __builtin_amdgcn_mfma_f32_16x16x32_bf16(ca2, cb2, acc, 0, 0, 0);
      if (lk < 2) {                              // rows 0..7 (8..15 are dups)
        int o = (OB16 * (gbase + j) + oln) & 4095;
        ushort4 h;
        h.x = f2bf(acc[0]); h.y = f2bf(acc[1]);
        h.z = f2bf(acc[2]); h.w = f2bf(acc[3]);
        *reinterpret_cast<ushort4*>(res + o * RSTRF + 4 * lk) = h;
      }
    }
    __syncthreads();   // xl reuse next chunk; after last iter: res complete
  }

  // ---- epilogue: out[b0+r][o] = res[o][r] + bias[o] ----
  // lane = (ol, j): b32 read at byte 16o+4j -> bank 4(o&7)+j: 2-way max.
  const int j  = lane & 3;          // row pair 2j, 2j+1
  const int ol = lane >> 2;         // 0..15 consecutive o
#pragma unroll 4
  for (int it = 0; it < 32; ++it) {
    int o = it * 128 + wave * 16 + ol;
    unsigned int v = *reinterpret_cast<const unsigned int*>(res + o * RSTRF + 2 * j);
    float b = bias[o];
    float lo = bf2f((unsigned short)(v & 0xffff)) + b;
    float hi = bf2f((unsigned short)(v >> 16)) + b;
    size_t base = (size_t)(b0 + 2 * j) * OUT_F + o;
    out[base]         = lo;
    out[base + OUT_F] = hi;
  }
}

extern "C" void kernel_launch(void* const* d_in, const int* in_sizes, int n_in,
                              void* d_out, int out_size, void* d_ws, size_t ws_size,
                              hipStream_t stream) {
  const float* x    = (const float*)d_in[0];
  const float* w    = (const float*)d_in[1];
  const float* bias = (const float*)d_in[2];
  const float* mask = (const float*)d_in[3];
  float* out = (float*)d_out;

  unsigned short* wfrag = (unsigned short*)d_ws;   // 786432 B

  const int B = in_sizes[0] / IN_F;                // 16384

  prep_wfrag<<<192, 256, 0, stream>>>(w, mask, wfrag);
  sc_fused<<<B / BMF, 512, 0, stream>>>(x, bias, wfrag, out);
}

// Round 8
// 156.802 us; speedup vs baseline: 1.5758x; 1.0721x over previous
//
#include <hip/hip_runtime.h>
#include <hip/hip_bf16.h>

#define IN_F 4096
#define OUT_F 4096
#define CPN 81
#define OINV 2225   // 81^{-1} mod 4096
#define OB16 2832   // 2225*16 mod 4096: o-step per group

#define BMF 8       // batch rows per block
#define NCH 8       // chunks per block
#define CHUNK 512   // band-starts (and x cols) per chunk
#define SC4 148     // float4 staged per row per chunk (592 cols)
#define NLD 1184    // BMF*SC4 total float4 loads per chunk
#define XSTR 616    // x LDS stride in bf16 elems
#define RSTRF 8     // res stride in bf16 elems (16 B per o-row)

typedef __attribute__((ext_vector_type(4))) float f32x4;
typedef __attribute__((ext_vector_type(8))) short bf16x8;

__device__ __forceinline__ unsigned short f2bf(float f) {
  __hip_bfloat16 h = __float2bfloat16(f);
  return *reinterpret_cast<unsigned short*>(&h);
}
__device__ __forceinline__ float bf2f(unsigned short u) {
  unsigned int v = ((unsigned int)u) << 16;
  return *reinterpret_cast<float*>(&v);
}

// ---- prep: pack weight*mask into MFMA B-fragment order ----
__global__ void prep_wfrag(const float* __restrict__ w,
                           const float* __restrict__ mask,
                           unsigned short* __restrict__ wfrag) {
  int idx = blockIdx.x * 256 + threadIdx.x;   // 49152 threads
  int lane = idx & 63;
  int t = (idx >> 6) % 3;
  int g = idx / 192;
  int n = lane & 15;
  int kg = lane >> 4;
  int s = g * 16 + n;
  int o = (OINV * s) & 4095;
  unsigned short v8[8];
#pragma unroll
  for (int i = 0; i < 8; ++i) {
    int c = 32 * t + 8 * kg + i;
    int j = c - n;
    float v = 0.f;
    if (j >= 0 && j < CPN) {
      int col = (16 * g + c) & 4095;
      v = w[(size_t)o * IN_F + col] * mask[(size_t)o * IN_F + col];
    }
    v8[i] = f2bf(v);
  }
  *reinterpret_cast<bf16x8*>(wfrag + (size_t)idx * 8) =
      *reinterpret_cast<const bf16x8*>(v8);
}

// ---- fused, ping-pong register pipeline ----
__global__ __launch_bounds__(512, 4) void sc_fused(
    const float* __restrict__ x, const float* __restrict__ bias,
    const unsigned short* __restrict__ wfrag, float* __restrict__ out) {
  __shared__ unsigned short res[4096 * RSTRF];   // 65536 B: [o][row] bf16
  __shared__ unsigned short xl[BMF * XSTR];      //  9856 B

  const int blk = blockIdx.x;        // 0..2047
  const int b0 = blk * BMF;
  const int tid = threadIdx.x;
  const int wave = tid >> 6;         // 0..7
  const int lane = tid & 63;
  const int ln = lane & 15;          // MFMA n index (s offset)
  const int lk = lane >> 4;          // k-group / D row quad
  const int oln = (OINV * ln) & 4095;
  const int q0 = blk & 7;            // stagger chunk order across blocks

  // hoisted staging coordinates (3 load slots per thread)
  const int i1 = tid + 512, i2 = tid + 1024;
  const int row0 = tid / SC4, c40 = tid - row0 * SC4;
  const int row1 = i1  / SC4, c41 = i1  - row1 * SC4;
  const int row2 = i2  / SC4, c42 = i2  - row2 * SC4;
  const bool v2 = (i2 < NLD);
  const float* xp0 = x + (size_t)(b0 + row0) * IN_F;
  const float* xp1 = x + (size_t)(b0 + row1) * IN_F;
  const float* xp2 = x + (size_t)(b0 + row2) * IN_F;
  unsigned short* xw0 = xl + row0 * XSTR + 4 * c40;
  unsigned short* xw1 = xl + row1 * XSTR + 4 * c41;
  unsigned short* xw2 = xl + row2 * XSTR + 4 * c42;

  auto loadx = [&](int q, float4& r0, float4& r1, float4& r2) {
    const int c0 = q * CHUNK;
    r0 = *reinterpret_cast<const float4*>(xp0 + ((c0 + 4 * c40) & 4095));
    r1 = *reinterpret_cast<const float4*>(xp1 + ((c0 + 4 * c41) & 4095));
    if (v2) r2 = *reinterpret_cast<const float4*>(xp2 + ((c0 + 4 * c42) & 4095));
  };
  auto drain = [&](const float4& r0, const float4& r1, const float4& r2) {
    ushort4 h;
    h.x = f2bf(r0.x); h.y = f2bf(r0.y); h.z = f2bf(r0.z); h.w = f2bf(r0.w);
    *reinterpret_cast<ushort4*>(xw0) = h;
    h.x = f2bf(r1.x); h.y = f2bf(r1.y); h.z = f2bf(r1.z); h.w = f2bf(r1.w);
    *reinterpret_cast<ushort4*>(xw1) = h;
    if (v2) {
      h.x = f2bf(r2.x); h.y = f2bf(r2.y); h.z = f2bf(r2.z); h.w = f2bf(r2.w);
      *reinterpret_cast<ushort4*>(xw2) = h;
    }
  };
  auto compute = [&](int q) {
    const int gbase = q * 32 + wave * 4;
    const bf16x8* wf = reinterpret_cast<const bf16x8*>(wfrag)
                     + (size_t)gbase * 192 + lane;
    const unsigned short* ap = xl + (ln & 7) * XSTR + 8 * lk + 16 * (wave * 4);
    bf16x8 nb0 = wf[0], nb1 = wf[64], nb2 = wf[128];
    bf16x8 na0 = *reinterpret_cast<const bf16x8*>(ap);
    bf16x8 na1 = *reinterpret_cast<const bf16x8*>(ap + 32);
    bf16x8 na2 = *reinterpret_cast<const bf16x8*>(ap + 64);
#pragma unroll
    for (int j = 0; j < 4; ++j) {
      bf16x8 cb0 = nb0, cb1 = nb1, cb2 = nb2;
      bf16x8 ca0 = na0, ca1 = na1, ca2 = na2;
      if (j < 3) {
        const bf16x8* nwf = wf + (j + 1) * 192;
        nb0 = nwf[0]; nb1 = nwf[64]; nb2 = nwf[128];
        const unsigned short* nap = ap + 16 * (j + 1);
        na0 = *reinterpret_cast<const bf16x8*>(nap);
        na1 = *reinterpret_cast<const bf16x8*>(nap + 32);
        na2 = *reinterpret_cast<const bf16x8*>(nap + 64);
      }
      f32x4 acc = f32x4{0.f, 0.f, 0.f, 0.f};
      acc = __builtin_amdgcn_mfma_f32_16x16x32_bf16(ca0, cb0, acc, 0, 0, 0);
      acc = __builtin_amdgcn_mfma_f32_16x16x32_bf16(ca1, cb1, acc, 0, 0, 0);
      acc = __builtin_amdgcn_mfma_f32_16x16x32_bf16(ca2, cb2, acc, 0, 0, 0);
      if (lk < 2) {                              // rows 0..7 (8..15 are dups)
        int o = (OB16 * (gbase + j) + oln) & 4095;
        ushort4 h;
        h.x = f2bf(acc[0]); h.y = f2bf(acc[1]);
        h.z = f2bf(acc[2]); h.w = f2bf(acc[3]);
        *reinterpret_cast<ushort4*>(res + o * RSTRF + 4 * lk) = h;
      }
    }
  };

  // ping-pong register sets A/B; loads pinned early by sched_barrier(0)
  float4 A0, A1, A2, B0, B1, B2;
  loadx(q0, A0, A1, A2);

  for (int qq = 0; qq < NCH; qq += 2) {
    const int qa = (q0 + qq) & 7;
    const int qb = (q0 + qq + 1) & 7;

    loadx(qb, B0, B1, B2);                 // issue early...
    __builtin_amdgcn_sched_barrier(0);     // ...and pin: cannot sink below
    drain(A0, A1, A2);
    __syncthreads();
    compute(qa);
    __syncthreads();

    if (qq + 2 < NCH) {
      loadx((q0 + qq + 2) & 7, A0, A1, A2);
      __builtin_amdgcn_sched_barrier(0);
    }
    drain(B0, B1, B2);
    __syncthreads();
    compute(qb);
    __syncthreads();
  }

  // ---- epilogue: out[b0+r][o] = res[o][r] + bias[o] ----
  // lane = (ol, j): b32 read at byte 16o+4j -> bank 4(o&7)+j: 2-way max.
  const int j  = lane & 3;          // row pair 2j, 2j+1
  const int ol = lane >> 2;         // 0..15 consecutive o
#pragma unroll 4
  for (int it = 0; it < 32; ++it) {
    int o = it * 128 + wave * 16 + ol;
    unsigned int v = *reinterpret_cast<const unsigned int*>(res + o * RSTRF + 2 * j);
    float b = bias[o];
    float lo = bf2f((unsigned short)(v & 0xffff)) + b;
    float hi = bf2f((unsigned short)(v >> 16)) + b;
    size_t base = (size_t)(b0 + 2 * j) * OUT_F + o;
    out[base]         = lo;
    out[base + OUT_F] = hi;
  }
}

extern "C" void kernel_launch(void* const* d_in, const int* in_sizes, int n_in,
                              void* d_out, int out_size, void* d_ws, size_t ws_size,
                              hipStream_t stream) {
  const float* x    = (const float*)d_in[0];
  const float* w    = (const float*)d_in[1];
  const float* bias = (const float*)d_in[2];
  const float* mask = (const float*)d_in[3];
  float* out = (float*)d_out;

  unsigned short* wfrag = (unsigned short*)d_ws;   // 786432 B

  const int B = in_sizes[0] / IN_F;                // 16384

  prep_wfrag<<<192, 256, 0, stream>>>(w, mask, wfrag);
  sc_fused<<<B / BMF, 512, 0, stream>>>(x, bias, wfrag, out);
}